// Round 11
// baseline (194.976 us; speedup 1.0000x reference)
//
#include <hip/hip_runtime.h>

// Problem constants
#define DIMC 1024
#define SEQL 2048
#define NB   2
#define NH   16
#define HD   64
#define MTOT (NB*SEQL)          // 4096 rows
#define XSTR 2048               // q/k interleaved: [q 1024 | k 1024] per row
static constexpr float SM_SCALE = 0.125f;             // HEAD_DIM^-0.5
static constexpr float LOG2E    = 1.4426950408889634f;
static constexpr float QSCALE   = SM_SCALE * LOG2E;   // folded into q at projection

typedef short s16x8 __attribute__((ext_vector_type(8)));
typedef short s16x4 __attribute__((ext_vector_type(4)));
typedef float f32x4 __attribute__((ext_vector_type(4)));
typedef int   i32x4 __attribute__((ext_vector_type(4)));

__device__ __forceinline__ unsigned short f2bf(float f) {
    unsigned int u = __float_as_uint(f);
    u += 0x7fffu + ((u >> 16) & 1u);   // round-to-nearest-even
    return (unsigned short)(u >> 16);
}
__device__ __forceinline__ s16x8 ld8(const unsigned short* p) {
    return *(const s16x8*)p;           // 16B global_load_dwordx4 (bf16 x8)
}
// async global->LDS, 16B per lane
__device__ __forceinline__ void gld_lds16(const unsigned short* g, unsigned short* l) {
    __builtin_amdgcn_global_load_lds(
        (const __attribute__((address_space(1))) void*)g,
        (__attribute__((address_space(3))) void*)l, 16, 0, 0);
}
// pack two f32 -> one u32 of 2x bf16 (RNE); no builtin on gfx950
__device__ __forceinline__ unsigned int cvtpk(float lo, float hi) {
    unsigned int r;
    asm("v_cvt_pk_bf16_f32 %0, %1, %2" : "=v"(r) : "v"(lo), "v"(hi));
    return r;
}

#define BAR()     asm volatile("s_barrier" ::: "memory")
#define WAITVM8() asm volatile("s_waitcnt vmcnt(8)" ::: "memory")
#define WAITVM4() asm volatile("s_waitcnt vmcnt(4)" ::: "memory")
#define WAITVM0() asm volatile("s_waitcnt vmcnt(0)" ::: "memory")

// ---------------------------------------------------------------------------
// One-shot prep: x -> bf16 (blocks 0..4095), W's -> bf16 (blocks 4096..8191),
// qkv bias pack fp32 (blocks 8192+).  UNCHANGED from R9 (passed).
// ---------------------------------------------------------------------------
__global__ __launch_bounds__(256) void cast_all(
    const float* __restrict__ x,
    const float* __restrict__ Wq, const float* __restrict__ Wk,
    const float* __restrict__ Wv, const float* __restrict__ Wp,
    const float* __restrict__ bq, const float* __restrict__ bk,
    const float* __restrict__ bvv,
    unsigned short* __restrict__ xb, unsigned short* __restrict__ wall,
    float* __restrict__ ball)
{
    const int bid = blockIdx.x, tid = threadIdx.x;
    if (bid < 4096) {
        int i = bid * 256 + tid;                 // x: 1M float4
        float4 f = ((const float4*)x)[i];
        s16x4 o;
        o[0] = (short)f2bf(f.x); o[1] = (short)f2bf(f.y);
        o[2] = (short)f2bf(f.z); o[3] = (short)f2bf(f.w);
        ((s16x4*)xb)[i] = o;
    } else if (bid < 8192) {
        int j = (bid - 4096) * 256 + tid;        // W: 1M float4 over 4 mats
        int r = j >> 18;                         // 256K float4 per matrix
        const float* src = (r == 0) ? Wq : (r == 1) ? Wk : (r == 2) ? Wv : Wp;
        float4 f = ((const float4*)src)[j & 262143];
        s16x4 o;
        o[0] = (short)f2bf(f.x); o[1] = (short)f2bf(f.y);
        o[2] = (short)f2bf(f.z); o[3] = (short)f2bf(f.w);
        ((s16x4*)wall)[j] = o;
    } else {
        int t2 = (bid - 8192) * 256 + tid;
        if (t2 < 3072)
            ball[t2] = (t2 < 1024) ? bq[t2]
                     : (t2 < 2048) ? bk[t2 - 1024] : bvv[t2 - 2048];
    }
}

// ---------------------------------------------------------------------------
// R6/R8/R9 verified 256x256 8-phase QKV GEMM. UNCHANGED from R9 (passed).
// ---------------------------------------------------------------------------
__global__ __launch_bounds__(512, 2) void qkv8(
    const unsigned short* __restrict__ A,     // xb, stride 1024
    const unsigned short* __restrict__ Wb,    // [Wq|Wk|Wv] rows
    const float* __restrict__ bias,
    unsigned short* __restrict__ qk, unsigned short* __restrict__ vtb)
{
    extern __shared__ __align__(16) unsigned short lds[];
    unsigned short* lA = lds;                 // 32768 elems (64 KB)
    unsigned short* lB = lds + 32768;         // 32768 elems (64 KB)

    const int t    = threadIdx.x;
    const int lane = t & 63;
    const int l15  = lane & 15;
    const int quad = lane >> 4;
    const int w    = t >> 6;                  // wave 0..7
    const int wm   = w >> 2;                  // 0..1 (M half)
    const int wn   = w & 3;                   // 0..3 (N quarter)

    // XCD-chunked bijective mapping: 192 blocks = 8 XCDs x 24
    const int xcd = blockIdx.x & 7;
    const int lb  = xcd * 24 + (blockIdx.x >> 3);   // 0..191, nt-major
    const int nt  = lb >> 4;                  // 0..11 (256-col panel)
    const int mt  = lb & 15;                  // 0..15 (256-row panel)
    const int row0 = mt * 256;

    // staging geometry: thread t covers row (t>>2) (+128 for 2nd issue),
    // LDS chunk c = t&3; global col pre-swizzled: logical = c ^ ((row>>1)&3)
    const int scol = (((t & 3) ^ ((t >> 3) & 3)) * 8);
    const unsigned short* gaQ = A  + (size_t)(row0 + (t >> 2)) * 1024 + scol;
    const unsigned short* gbQ = Wb + (size_t)(nt * 256 + (t >> 2)) * 1024 + scol;

    // read-side swizzle: chunk = quad ^ ((l15>>1)&3)
    const int xq = (quad ^ ((l15 >> 1) & 3)) * 8;

    f32x4 acc[8][4] = {};

    // stage unit: A or B, K-half ks of K-tile kt2, into buffer b (2 loads)
    auto stA = [&](int b, int ks, int kt2) {
        const unsigned short* s = gaQ + (size_t)kt2 * 64 + ks * 32;
        unsigned short* d = lA + (size_t)(b * 2 + ks) * 8192 + t * 8;
        gld_lds16(s, d);
        gld_lds16(s + (size_t)128 * 1024, d + 4096);
    };
    auto stB = [&](int b, int ks, int kt2) {
        const unsigned short* s = gbQ + (size_t)kt2 * 64 + ks * 32;
        unsigned short* d = lB + (size_t)(b * 2 + ks) * 8192 + t * 8;
        gld_lds16(s, d);
        gld_lds16(s + (size_t)128 * 1024, d + 4096);
    };

    // one phase: 12 ds_reads | issue | vmcnt | barrier | 16 MFMA | barrier
    auto doPhase = [&](const unsigned short* Ak, const unsigned short* Bk,
                       int mh, auto&& iss, int vm) {
        s16x8 fa[4], fb[4];
#pragma unroll
        for (int m = 0; m < 4; ++m)
            fa[m] = *(const s16x8*)(Ak + (wm * 128 + mh * 64 + m * 16 + l15) * 32 + xq);
#pragma unroll
        for (int n = 0; n < 4; ++n)
            fb[n] = *(const s16x8*)(Bk + (wn * 64 + n * 16 + l15) * 32 + xq);
        iss();
        if (vm == 8)      WAITVM8();
        else if (vm == 4) WAITVM4();
        else if (vm == 0) WAITVM0();
        BAR();
        __builtin_amdgcn_s_setprio(1);
#pragma unroll
        for (int m = 0; m < 4; ++m)
#pragma unroll
            for (int n = 0; n < 4; ++n)
                acc[mh * 4 + m][n] = __builtin_amdgcn_mfma_f32_16x16x32_bf16(
                    fa[m], fb[n], acc[mh * 4 + m][n], 0, 0, 0);
        __builtin_amdgcn_s_setprio(0);
        BAR();
    };

    // one K-tile = 4 phases. mode 0: steady; 1: tile 14; 2: tile 15 (tail)
    auto tile = [&](int b, int kt, int mode) {
        const unsigned short* Ak0 = lA + (size_t)b * 16384;
        const unsigned short* Bk0 = lB + (size_t)b * 16384;
        doPhase(Ak0, Bk0, 0, [&] { if (mode < 2) stA(b ^ 1, 1, kt + 1); }, -1);
        doPhase(Ak0, Bk0, 1, [&] { if (mode < 2) stB(b ^ 1, 1, kt + 1); },
                mode == 2 ? 0 : 8);
        doPhase(Ak0 + 8192, Bk0 + 8192, 0, [&] { if (mode == 0) stA(b, 0, kt + 2); }, -1);
        doPhase(Ak0 + 8192, Bk0 + 8192, 1, [&] { if (mode == 0) stB(b, 0, kt + 2); },
                mode == 0 ? 8 : (mode == 1 ? 4 : -1));
    };

    // prologue: tile0 all 4 units + tile1 Ak0,Bk0 (12 loads); retire tile0
    stA(0, 0, 0); stB(0, 0, 0);
    stA(0, 1, 0); stB(0, 1, 0);
    stA(1, 0, 1); stB(1, 0, 1);
    WAITVM4();
    BAR();

#pragma unroll 1
    for (int kt = 0; kt < 14; kt += 2) {
        tile(0, kt, 0);
        tile(1, kt + 1, 0);
    }
    tile(0, 14, 1);
    tile(1, 15, 2);

    // epilogue (same store paths as the 128^2 kernel)
    const int proj = nt >> 2;                  // 0=q 1=k 2=v
#pragma unroll
    for (int ni = 0; ni < 4; ++ni) {
        const int cq = (nt & 3) * 256 + wn * 64 + ni * 16 + l15;   // col in proj
        const float bz = bias[proj * 1024 + cq];
#pragma unroll
        for (int mi = 0; mi < 8; ++mi) {
            const int rbase = row0 + wm * 128 + mi * 16 + quad * 4;
            if (proj < 2) {
                const float scale = (proj == 0) ? QSCALE : 1.0f;
#pragma unroll
                for (int r = 0; r < 4; ++r)
                    qk[(size_t)(rbase + r) * XSTR + proj * DIMC + cq] =
                        f2bf((acc[mi][ni][r] + bz) * scale);
            } else {
                const int h = cq >> 6, d = cq & 63;
                const int bb2 = rbase >> 11, ll = rbase & (SEQL - 1);
                s16x4 v4;
                v4[0] = (short)f2bf(acc[mi][ni][0] + bz);
                v4[1] = (short)f2bf(acc[mi][ni][1] + bz);
                v4[2] = (short)f2bf(acc[mi][ni][2] + bz);
                v4[3] = (short)f2bf(acc[mi][ni][3] + bz);
                *(s16x4*)(vtb + ((size_t)((bb2 * NH + h) * HD + d)) * SEQL + ll) = v4;
            }
        }
    }
}

// ---------------------------------------------------------------------------
// 128x128-tile NT GEMM (R5 version, unchanged) -- out-proj only.
// ---------------------------------------------------------------------------
__global__ __launch_bounds__(256) void gemm_tile(
    const unsigned short* __restrict__ A, int astride,
    const unsigned short* __restrict__ Wb,
    const float* __restrict__ bias,
    unsigned short* qk, unsigned short* vtb, float* outf, int mode)
{
    __shared__ __align__(16) unsigned short Asm[3][128 * 32];   // 3x8 KB
    __shared__ __align__(16) unsigned short Bsm[3][128 * 32];   // 3x8 KB

    const int t    = threadIdx.x;
    const int lane = t & 63;
    const int l15  = lane & 15;
    const int quad = lane >> 4;
    const int w    = t >> 6;
    const int mrow = (w & 1) * 64;
    const int ncol = (w >> 1) * 64;
    const int nt_total = (int)gridDim.x >> 5;
    const int xcd = blockIdx.x & 7;
    const int i2  = blockIdx.x >> 3;
    const int nt  = xcd * (nt_total >> 3) + (i2 >> 5);
    const int mt  = i2 & 31;
    const int row0 = mt * 128;

    const unsigned short* ga = A  + (size_t)(row0 + (t >> 2)) * astride + (t & 3) * 8;
    const unsigned short* gb = Wb + (size_t)(nt * 128 + (t >> 2)) * DIMC + (t & 3) * 8;
    const size_t gaStep = (size_t)64 * astride;
    const size_t gbStep = (size_t)64 * DIMC;

    f32x4 acc[4][4] = {};

    auto stage = [&](unsigned short* Ab, unsigned short* Bb, int k0) {
        gld_lds16(ga + k0,          Ab + t * 8);
        gld_lds16(ga + gaStep + k0, Ab + 2048 + t * 8);
        gld_lds16(gb + k0,          Bb + t * 8);
        gld_lds16(gb + gbStep + k0, Bb + 2048 + t * 8);
    };

    auto compute = [&](const unsigned short* Ac, const unsigned short* Bc) {
        s16x8 a[4], b[4];
#pragma unroll
        for (int mi = 0; mi < 4; ++mi)
            a[mi] = *(const s16x8*)(Ac + (mrow + mi * 16 + l15) * 32 + quad * 8);
#pragma unroll
        for (int ni = 0; ni < 4; ++ni)
            b[ni] = *(const s16x8*)(Bc + (ncol + ni * 16 + l15) * 32 + quad * 8);
        __builtin_amdgcn_s_setprio(1);
#pragma unroll
        for (int mi = 0; mi < 4; ++mi)
#pragma unroll
            for (int ni = 0; ni < 4; ++ni)
                acc[mi][ni] = __builtin_amdgcn_mfma_f32_16x16x32_bf16(
                    a[mi], b[ni], acc[mi][ni], 0, 0, 0);
        __builtin_amdgcn_s_setprio(0);
    };

    stage(Asm[0], Bsm[0], 0);
    stage(Asm[1], Bsm[1], 32);

#pragma unroll 1
    for (int k0 = 0; k0 < 960; k0 += 96) {
        stage(Asm[2], Bsm[2], k0 + 64);
        WAITVM8();
        BAR();
        compute(Asm[0], Bsm[0]);
        BAR();
        stage(Asm[0], Bsm[0], k0 + 96);
        WAITVM8();
        BAR();
        compute(Asm[1], Bsm[1]);
        BAR();
        stage(Asm[1], Bsm[1], k0 + 128);
        WAITVM8();
        BAR();
        compute(Asm[2], Bsm[2]);
        BAR();
    }
    WAITVM4();
    BAR();
    compute(Asm[0], Bsm[0]);
    BAR();
    WAITVM0();
    BAR();
    compute(Asm[1], Bsm[1]);

    const int proj = nt >> 3;
#pragma unroll
    for (int ni = 0; ni < 4; ++ni) {
        const int cq = (nt & 7) * 128 + ncol + ni * 16 + l15;
        const float bz = bias[proj * 1024 + cq];
#pragma unroll
        for (int mi = 0; mi < 4; ++mi) {
            const int rbase = row0 + mrow + mi * 16 + quad * 4;
            if (mode == 0) {
                if (proj < 2) {
                    const float scale = (proj == 0) ? QSCALE : 1.0f;
#pragma unroll
                    for (int r = 0; r < 4; ++r)
                        qk[(size_t)(rbase + r) * XSTR + proj * DIMC + cq] =
                            f2bf((acc[mi][ni][r] + bz) * scale);
                } else {
                    const int h = cq >> 6, d = cq & 63;
                    const int bb = rbase >> 11, ll = rbase & (SEQL - 1);
                    s16x4 v4;
                    v4[0] = (short)f2bf(acc[mi][ni][0] + bz);
                    v4[1] = (short)f2bf(acc[mi][ni][1] + bz);
                    v4[2] = (short)f2bf(acc[mi][ni][2] + bz);
                    v4[3] = (short)f2bf(acc[mi][ni][3] + bz);
                    *(s16x4*)(vtb + ((size_t)((bb * NH + h) * HD + d)) * SEQL + ll) = v4;
                }
            } else {
#pragma unroll
                for (int r = 0; r < 4; ++r)
                    outf[(size_t)(rbase + r) * DIMC + cq] = acc[mi][ni][r] + bz;
            }
        }
    }
}

// ---------------------------------------------------------------------------
// Flash attention v11 (R9 PASSED version, byte-identical): 256 thr, 4 waves,
// 128 q-rows; KVBLK=128 windows (two verbatim 64-key tiles per barrier
// pair); counted-vmcnt dbuf; setprio; ones-l MFMA; cvt_pk pack. UNCHANGED.
// ---------------------------------------------------------------------------
__global__ __launch_bounds__(256) void attn_fused(
    unsigned short* xqk,
    const unsigned short* __restrict__ vt)
{
    __shared__ __align__(16) unsigned short Ksm[2][2][64 * 64];   // 32 KB
    __shared__ __align__(16) unsigned short Vsm[2][2][64 * 64];   // 32 KB

    const int t    = threadIdx.x;
    const int lane = t & 63;
    const int l15  = lane & 15;
    const int quad = lane >> 4;
    const int w    = t >> 6;                 // wave 0..3

    // XCD-pinned mapping (bijective: bid = ii*8 + xcd), 512 blocks
    const int xcd = blockIdx.x & 7;
    const int ii  = blockIdx.x >> 3;         // 0..63
    const int bh  = (xcd << 2) | (ii >> 4);  // all 16 q-blocks of a bh on one XCD
    const int qb  = ii & 15;                 // 128-row q-block
    const int h  = bh & (NH - 1);
    const int bb = bh >> 4;
    const int q0A = qb * 128 + w * 16;       // wave's two q-tiles
    const int q0B = q0A + 64;

    // Q B-frags (lane&15 = q row), loaded before any O store (in-place safe)
    unsigned short* qbase = xqk + (size_t)(bb * SEQL) * XSTR + h * HD + quad * 8;
    unsigned short* qrA = qbase + (size_t)(q0A + l15) * XSTR;
    unsigned short* qrB = qbase + (size_t)(q0B + l15) * XSTR;
    const s16x8 bqA0 = ld8(qrA), bqA1 = ld8(qrA + 32);
    const s16x8 bqB0 = ld8(qrB), bqB1 = ld8(qrB + 32);

    // all-ones bf16 B-frag for the l-accumulation MFMA
    s16x8 bones;
#pragma unroll
    for (int e = 0; e < 8; ++e) bones[e] = (short)0x3F80;

    // staging: 256 threads cover a 64x64 tile in 2 row-groups of 32.
    const int tr = t >> 3, tp = t & 7;
    const int swz = (tp ^ (tr & 7)) * 8;
    const unsigned short* kg = xqk + (size_t)bb * SEQL * XSTR + DIMC + h * HD
                               + (size_t)tr * XSTR + swz;
    const unsigned short* vg = vt + (size_t)(bh * HD + tr) * SEQL + swz;

    f32x4 oA[4] = {}, oB[4] = {};
    f32x4 laccA = {}, laccB = {};            // row-sums of P (denominators)
    const int xk = l15 & 7;

    // stage one 64-key tile (K + V); 4 loads per thread
    auto stage = [&](unsigned short* Kb, unsigned short* Vb, int j) {
#pragma unroll
        for (int g = 0; g < 2; ++g) {
            gld_lds16(kg + (size_t)(j + g * 32) * XSTR, Kb + g * 2048 + t * 8);
            gld_lds16(vg + (size_t)(g * 32) * SEQL + j,  Vb + g * 2048 + t * 8);
        }
    };

    // compute one 64-key tile from buffers
    auto compute = [&](const unsigned short* Kc, const unsigned short* Vc) {
#pragma unroll
        for (int hf = 0; hf < 2; ++hf) {
            const int k0 = (hf * 32 + l15) * 64;
            const int k1 = (hf * 32 + 16 + l15) * 64;
            s16x8 a00 = *(const s16x8*)(Kc + k0 + ((quad       ^ xk) * 8));
            s16x8 a01 = *(const s16x8*)(Kc + k0 + (((quad + 4) ^ xk) * 8));
            s16x8 a10 = *(const s16x8*)(Kc + k1 + ((quad       ^ xk) * 8));
            s16x8 a11 = *(const s16x8*)(Kc + k1 + (((quad + 4) ^ xk) * 8));

            s16x8 bv[4];
#pragma unroll
            for (int c = 0; c < 4; ++c) {
                const unsigned short* va = Vc + (c * 16 + l15) * 64 + (quad & 1) * 4;
                const int kc0 = hf * 4 + (quad >> 1);
                s16x4 v0 = *(const s16x4*)(va + ((kc0       ^ xk) * 8));
                s16x4 v1 = *(const s16x4*)(va + (((kc0 + 2) ^ xk) * 8));
                bv[c] = __builtin_shufflevector(v0, v1, 0, 1, 2, 3, 4, 5, 6, 7);
            }

            __builtin_amdgcn_s_setprio(1);
            // q-tile A
            {
                f32x4 st0 = {}, st1 = {};
                st0 = __builtin_amdgcn_mfma_f32_16x16x32_bf16(a00, bqA0, st0, 0, 0, 0);
                st0 = __builtin_amdgcn_mfma_f32_16x16x32_bf16(a01, bqA1, st0, 0, 0, 0);
                st1 = __builtin_amdgcn_mfma_f32_16x16x32_bf16(a10, bqA0, st1, 0, 0, 0);
                st1 = __builtin_amdgcn_mfma_f32_16x16x32_bf16(a11, bqA1, st1, 0, 0, 0);
                i32x4 api;
                api[0] = (int)cvtpk(__builtin_amdgcn_exp2f(st0[0]),
                                    __builtin_amdgcn_exp2f(st0[1]));
                api[1] = (int)cvtpk(__builtin_amdgcn_exp2f(st0[2]),
                                    __builtin_amdgcn_exp2f(st0[3]));
                api[2] = (int)cvtpk(__builtin_amdgcn_exp2f(st1[0]),
                                    __builtin_amdgcn_exp2f(st1[1]));
                api[3] = (int)cvtpk(__builtin_amdgcn_exp2f(st1[2]),
                                    __builtin_amdgcn_exp2f(st1[3]));
                s16x8 ap = __builtin_bit_cast(s16x8, api);
                laccA = __builtin_amdgcn_mfma_f32_16x16x32_bf16(ap, bones, laccA, 0, 0, 0);
#pragma unroll
                for (int c = 0; c < 4; ++c)
                    oA[c] = __builtin_amdgcn_mfma_f32_16x16x32_bf16(ap, bv[c], oA[c], 0, 0, 0);
            }
            // q-tile B
            {
                f32x4 st0 = {}, st1 = {};
                st0 = __builtin_amdgcn_mfma_f32_16x16x32_bf16(a00, bqB0, st0, 0, 0, 0);
                st0 = __builtin_amdgcn_mfma_f32_16x16x32_bf16(a01, bqB1, st0, 0, 0, 0);
                st1 = __builtin_amdgcn_mfma_f32_16x16x32_bf16(a10, bqB0, st1, 0, 0, 0);
                st1 = __builtin_amdgcn_mfma_f32_16x16x32_bf16(a11, bqB1, st1, 0, 0, 0);
                i32x4 api;
                api[0] = (int)cvtpk(__builtin_amdgcn_exp2f(st0[0]),
                                    __builtin_amdgcn_exp2f(st0[1]));
                api[1] = (int)cvtpk(__builtin_amdgcn_exp2f(st0[2]),
                                    __builtin_amdgcn_exp2f(st0[3]));
                api[2] = (int)cvtpk(__builtin_amdgcn_exp2f(st1[0]),
                                    __builtin_amdgcn_exp2f(st1[1]));
                api[3] = (int)cvtpk(__builtin_amdgcn_exp2f(st1[2]),
                                    __builtin_amdgcn_exp2f(st1[3]));
                s16x8 ap = __builtin_bit_cast(s16x8, api);
                laccB = __builtin_amdgcn_mfma_f32_16x16x32_bf16(ap, bones, laccB, 0, 0, 0);
#pragma unroll
                for (int c = 0; c < 4; ++c)
                    oB[c] = __builtin_amdgcn_mfma_f32_16x16x32_bf16(ap, bv[c], oB[c], 0, 0, 0);
            }
            __builtin_amdgcn_s_setprio(0);
        }
    };

    // prologue: stage both halves of window 0 into buffer 0 (8 loads)
    stage(Ksm[0][0], Vsm[0][0], 0);
    stage(Ksm[0][1], Vsm[0][1], 64);

    // main loop over 16 x 128-key windows, unroll-2 (compile-time buffers).
#pragma unroll 1
    for (int jt = 0; jt < SEQL / 128; jt += 2) {
        const int j0 = jt * 128;
        // body A: prefetch window jt+1 -> buf1, compute buf0 (window jt)
        stage(Ksm[1][0], Vsm[1][0], j0 + 128);
        stage(Ksm[1][1], Vsm[1][1], j0 + 192);
        WAITVM8();
        BAR();
        compute(Ksm[0][0], Vsm[0][0]);
        compute(Ksm[0][1], Vsm[0][1]);
        BAR();
        // body B: prefetch window jt+2 -> buf0, compute buf1 (window jt+1)
        if (jt + 2 < SEQL / 128) {
            stage(Ksm[0][0], Vsm[0][0], j0 + 256);
            stage(Ksm[0][1], Vsm[0][1], j0 + 320);
            WAITVM8();
        } else {
            WAITVM0();
        }
        BAR();
        compute(Ksm[1][0], Vsm[1][0]);
        compute(Ksm[1][1], Vsm[1][1]);
        BAR();
    }

    // laccX[r] = l for q-row quad*4+r (replicated across l15) -> no shuffles
    float liA[4], liB[4];
#pragma unroll
    for (int r = 0; r < 4; ++r) {
        liA[r] = 1.0f / laccA[r];
        liB[r] = 1.0f / laccB[r];
    }

#pragma unroll
    for (int c = 0; c < 4; ++c) {
        const int d = c * 16 + l15;
#pragma unroll
        for (int r = 0; r < 4; ++r) {
            const int qr = quad * 4 + r;
            xqk[(size_t)(bb * SEQL + q0A + qr) * XSTR + h * HD + d] = f2bf(oA[c][r] * liA[r]);
            xqk[(size_t)(bb * SEQL + q0B + qr) * XSTR + h * HD + d] = f2bf(oB[c][r] * liB[r]);
        }
    }
}

// ---------------------------------------------------------------------------
// R11 single-variable experiment: kernels are BYTE-IDENTICAL to R9 (passed);
// the ONLY change is xqk placement -- into d_ws (after xb|wall|bias) when
// ws_size permits, else fall back to d_in[0] (exact R9 behavior). If this
// round fails, the ws-xqk move is definitively indicted (kernels constant).
// ws layout (u16): xb [0,4M) | Wq..Wp [4M,8M) | bias fp32 @ 8M (6144 u16) |
// xqk @ 8M+8192 (8M u16).
// ---------------------------------------------------------------------------
extern "C" void kernel_launch(void* const* d_in, const int* in_sizes, int n_in,
                              void* d_out, int out_size, void* d_ws, size_t ws_size,
                              hipStream_t stream) {
    const float* x  = (const float*)d_in[0];
    const float* Wq = (const float*)d_in[1];
    const float* bq = (const float*)d_in[2];
    const float* Wk = (const float*)d_in[3];
    const float* bk = (const float*)d_in[4];
    const float* Wv = (const float*)d_in[5];
    const float* bv = (const float*)d_in[6];
    const float* Wp = (const float*)d_in[7];
    const float* bp = (const float*)d_in[8];
    float* out = (float*)d_out;
    unsigned short* vtb = (unsigned short*)d_out;

    unsigned short* ws   = (unsigned short*)d_ws;
    const size_t XELT = (size_t)MTOT * DIMC;     // 4M u16
    const size_t WELT = (size_t)DIMC * DIMC;     // 1M u16
    unsigned short* xb   = ws;
    unsigned short* wall = ws + XELT;
    float*          ball = (float*)(ws + 2 * XELT);
    const size_t xqkOff = 2 * XELT + 8192;       // after bias block, 16B-aligned
    const size_t needed = (xqkOff + (size_t)MTOT * XSTR) * sizeof(unsigned short);
    unsigned short* xqk = (ws_size >= needed) ? (ws + xqkOff)
                                              : (unsigned short*)d_in[0];

    // allow 128 KB dynamic LDS for qkv8 (one-time)
    static bool ldsInit = false;
    if (!ldsInit) {
        (void)hipFuncSetAttribute((const void*)qkv8,
                                  hipFuncAttributeMaxDynamicSharedMemorySize,
                                  131072);
        ldsInit = true;
    }

    cast_all<<<8204, 256, 0, stream>>>(x, Wq, Wk, Wv, Wp, bq, bk, bv, xb, wall, ball);

    // fused QKV GEMM: M=4096, N=3072 -> 16 x 12 tiles of 256^2 = 192 blocks
    qkv8<<<192, 512, 131072, stream>>>(xb, wall, ball, xqk, vtb);

    // attention: 512 blocks (32 bh x 16 q-blocks of 128 rows), 4 waves each
    attn_fused<<<NB * NH * (SEQL / 128), 256, 0, stream>>>(xqk, vtb);

    // out-proj: M=4096, N=1024 -> 256 blocks, fp32 out
    gemm_tile<<<256, 256, 0, stream>>>(xqk, XSTR, wall + 3 * WELT, bp,
                                       nullptr, nullptr, out, 1);
}

// Round 12
// 190.201 us; speedup vs baseline: 1.0251x; 1.0251x over previous
//
#include <hip/hip_runtime.h>

// Problem constants
#define DIMC 1024
#define SEQL 2048
#define NB   2
#define NH   16
#define HD   64
#define MTOT (NB*SEQL)          // 4096 rows
#define XSTR 2048               // q/k interleaved: [q 1024 | k 1024] per row
static constexpr float SM_SCALE = 0.125f;             // HEAD_DIM^-0.5
static constexpr float LOG2E    = 1.4426950408889634f;
static constexpr float QSCALE   = SM_SCALE * LOG2E;   // folded into q at projection

typedef short s16x8 __attribute__((ext_vector_type(8)));
typedef short s16x4 __attribute__((ext_vector_type(4)));
typedef float f32x4 __attribute__((ext_vector_type(4)));
typedef int   i32x4 __attribute__((ext_vector_type(4)));

__device__ __forceinline__ unsigned short f2bf(float f) {
    unsigned int u = __float_as_uint(f);
    u += 0x7fffu + ((u >> 16) & 1u);   // round-to-nearest-even
    return (unsigned short)(u >> 16);
}
__device__ __forceinline__ s16x8 ld8(const unsigned short* p) {
    return *(const s16x8*)p;           // 16B global_load_dwordx4 (bf16 x8)
}
// async global->LDS, 16B per lane
__device__ __forceinline__ void gld_lds16(const unsigned short* g, unsigned short* l) {
    __builtin_amdgcn_global_load_lds(
        (const __attribute__((address_space(1))) void*)g,
        (__attribute__((address_space(3))) void*)l, 16, 0, 0);
}
// pack two f32 -> one u32 of 2x bf16 (RNE); no builtin on gfx950
__device__ __forceinline__ unsigned int cvtpk(float lo, float hi) {
    unsigned int r;
    asm("v_cvt_pk_bf16_f32 %0, %1, %2" : "=v"(r) : "v"(lo), "v"(hi));
    return r;
}

#define BAR()     asm volatile("s_barrier" ::: "memory")
#define WAITVM8() asm volatile("s_waitcnt vmcnt(8)" ::: "memory")
#define WAITVM4() asm volatile("s_waitcnt vmcnt(4)" ::: "memory")
#define WAITVM0() asm volatile("s_waitcnt vmcnt(0)" ::: "memory")

// ---------------------------------------------------------------------------
// One-shot prep: x -> bf16 (blocks 0..4095), W's -> bf16 (blocks 4096..8191),
// qkv bias pack fp32 (blocks 8192+).  UNCHANGED (R9 passed).
// ---------------------------------------------------------------------------
__global__ __launch_bounds__(256) void cast_all(
    const float* __restrict__ x,
    const float* __restrict__ Wq, const float* __restrict__ Wk,
    const float* __restrict__ Wv, const float* __restrict__ Wp,
    const float* __restrict__ bq, const float* __restrict__ bk,
    const float* __restrict__ bvv,
    unsigned short* __restrict__ xb, unsigned short* __restrict__ wall,
    float* __restrict__ ball)
{
    const int bid = blockIdx.x, tid = threadIdx.x;
    if (bid < 4096) {
        int i = bid * 256 + tid;                 // x: 1M float4
        float4 f = ((const float4*)x)[i];
        s16x4 o;
        o[0] = (short)f2bf(f.x); o[1] = (short)f2bf(f.y);
        o[2] = (short)f2bf(f.z); o[3] = (short)f2bf(f.w);
        ((s16x4*)xb)[i] = o;
    } else if (bid < 8192) {
        int j = (bid - 4096) * 256 + tid;        // W: 1M float4 over 4 mats
        int r = j >> 18;                         // 256K float4 per matrix
        const float* src = (r == 0) ? Wq : (r == 1) ? Wk : (r == 2) ? Wv : Wp;
        float4 f = ((const float4*)src)[j & 262143];
        s16x4 o;
        o[0] = (short)f2bf(f.x); o[1] = (short)f2bf(f.y);
        o[2] = (short)f2bf(f.z); o[3] = (short)f2bf(f.w);
        ((s16x4*)wall)[j] = o;
    } else {
        int t2 = (bid - 8192) * 256 + tid;
        if (t2 < 3072)
            ball[t2] = (t2 < 1024) ? bq[t2]
                     : (t2 < 2048) ? bk[t2 - 1024] : bvv[t2 - 2048];
    }
}

// ---------------------------------------------------------------------------
// 256x256 8-phase QKV GEMM. R12 change (vs verified R9): 2D XCD chunking.
// Old nt-major chunk gave each XCD 0.75 MB of B but ALL 8 MB of A (> 4 MB L2)
// -> A-staging misses L2 (~900cy) and the 2-phase vmcnt cover can't hide it.
// New: each XCD owns a 4mt x 6nt sub-grid -> working set 2 MB A + 3 MB B,
// ~L2-fit; 24 co-resident blocks/XCD share it. Index math only; bijective:
// mt = (xcd&3)*4 + (i&3), nt = (xcd>>2)*6 + (i>>2). Everything else identical.
// ---------------------------------------------------------------------------
__global__ __launch_bounds__(512, 2) void qkv8(
    const unsigned short* __restrict__ A,     // xb, stride 1024
    const unsigned short* __restrict__ Wb,    // [Wq|Wk|Wv] rows
    const float* __restrict__ bias,
    unsigned short* __restrict__ qk, unsigned short* __restrict__ vtb)
{
    extern __shared__ __align__(16) unsigned short lds[];
    unsigned short* lA = lds;                 // 32768 elems (64 KB)
    unsigned short* lB = lds + 32768;         // 32768 elems (64 KB)

    const int t    = threadIdx.x;
    const int lane = t & 63;
    const int l15  = lane & 15;
    const int quad = lane >> 4;
    const int w    = t >> 6;                  // wave 0..7
    const int wm   = w >> 2;                  // 0..1 (M half)
    const int wn   = w & 3;                   // 0..3 (N quarter)

    // 2D XCD-chunked bijective mapping: 192 blocks = 8 XCDs x (4mt x 6nt)
    const int xcd = blockIdx.x & 7;
    const int i   = blockIdx.x >> 3;          // 0..23
    const int mt  = (xcd & 3) * 4 + (i & 3);  // 0..15 (256-row panel)
    const int nt  = (xcd >> 2) * 6 + (i >> 2);// 0..11 (256-col panel)
    const int row0 = mt * 256;

    // staging geometry: thread t covers row (t>>2) (+128 for 2nd issue),
    // LDS chunk c = t&3; global col pre-swizzled: logical = c ^ ((row>>1)&3)
    const int scol = (((t & 3) ^ ((t >> 3) & 3)) * 8);
    const unsigned short* gaQ = A  + (size_t)(row0 + (t >> 2)) * 1024 + scol;
    const unsigned short* gbQ = Wb + (size_t)(nt * 256 + (t >> 2)) * 1024 + scol;

    // read-side swizzle: chunk = quad ^ ((l15>>1)&3)
    const int xq = (quad ^ ((l15 >> 1) & 3)) * 8;

    f32x4 acc[8][4] = {};

    // stage unit: A or B, K-half ks of K-tile kt2, into buffer b (2 loads)
    auto stA = [&](int b, int ks, int kt2) {
        const unsigned short* s = gaQ + (size_t)kt2 * 64 + ks * 32;
        unsigned short* d = lA + (size_t)(b * 2 + ks) * 8192 + t * 8;
        gld_lds16(s, d);
        gld_lds16(s + (size_t)128 * 1024, d + 4096);
    };
    auto stB = [&](int b, int ks, int kt2) {
        const unsigned short* s = gbQ + (size_t)kt2 * 64 + ks * 32;
        unsigned short* d = lB + (size_t)(b * 2 + ks) * 8192 + t * 8;
        gld_lds16(s, d);
        gld_lds16(s + (size_t)128 * 1024, d + 4096);
    };

    // one phase: 12 ds_reads | issue | vmcnt | barrier | 16 MFMA | barrier
    auto doPhase = [&](const unsigned short* Ak, const unsigned short* Bk,
                       int mh, auto&& iss, int vm) {
        s16x8 fa[4], fb[4];
#pragma unroll
        for (int m = 0; m < 4; ++m)
            fa[m] = *(const s16x8*)(Ak + (wm * 128 + mh * 64 + m * 16 + l15) * 32 + xq);
#pragma unroll
        for (int n = 0; n < 4; ++n)
            fb[n] = *(const s16x8*)(Bk + (wn * 64 + n * 16 + l15) * 32 + xq);
        iss();
        if (vm == 8)      WAITVM8();
        else if (vm == 4) WAITVM4();
        else if (vm == 0) WAITVM0();
        BAR();
        __builtin_amdgcn_s_setprio(1);
#pragma unroll
        for (int m = 0; m < 4; ++m)
#pragma unroll
            for (int n = 0; n < 4; ++n)
                acc[mh * 4 + m][n] = __builtin_amdgcn_mfma_f32_16x16x32_bf16(
                    fa[m], fb[n], acc[mh * 4 + m][n], 0, 0, 0);
        __builtin_amdgcn_s_setprio(0);
        BAR();
    };

    // one K-tile = 4 phases. mode 0: steady; 1: tile 14; 2: tile 15 (tail)
    auto tile = [&](int b, int kt, int mode) {
        const unsigned short* Ak0 = lA + (size_t)b * 16384;
        const unsigned short* Bk0 = lB + (size_t)b * 16384;
        doPhase(Ak0, Bk0, 0, [&] { if (mode < 2) stA(b ^ 1, 1, kt + 1); }, -1);
        doPhase(Ak0, Bk0, 1, [&] { if (mode < 2) stB(b ^ 1, 1, kt + 1); },
                mode == 2 ? 0 : 8);
        doPhase(Ak0 + 8192, Bk0 + 8192, 0, [&] { if (mode == 0) stA(b, 0, kt + 2); }, -1);
        doPhase(Ak0 + 8192, Bk0 + 8192, 1, [&] { if (mode == 0) stB(b, 0, kt + 2); },
                mode == 0 ? 8 : (mode == 1 ? 4 : -1));
    };

    // prologue: tile0 all 4 units + tile1 Ak0,Bk0 (12 loads); retire tile0
    stA(0, 0, 0); stB(0, 0, 0);
    stA(0, 1, 0); stB(0, 1, 0);
    stA(1, 0, 1); stB(1, 0, 1);
    WAITVM4();
    BAR();

#pragma unroll 1
    for (int kt = 0; kt < 14; kt += 2) {
        tile(0, kt, 0);
        tile(1, kt + 1, 0);
    }
    tile(0, 14, 1);
    tile(1, 15, 2);

    // epilogue (same store paths as R9)
    const int proj = nt >> 2;                  // 0=q 1=k 2=v
#pragma unroll
    for (int ni = 0; ni < 4; ++ni) {
        const int cq = (nt & 3) * 256 + wn * 64 + ni * 16 + l15;   // col in proj
        const float bz = bias[proj * 1024 + cq];
#pragma unroll
        for (int mi = 0; mi < 8; ++mi) {
            const int rbase = row0 + wm * 128 + mi * 16 + quad * 4;
            if (proj < 2) {
                const float scale = (proj == 0) ? QSCALE : 1.0f;
#pragma unroll
                for (int r = 0; r < 4; ++r)
                    qk[(size_t)(rbase + r) * XSTR + proj * DIMC + cq] =
                        f2bf((acc[mi][ni][r] + bz) * scale);
            } else {
                const int h = cq >> 6, d = cq & 63;
                const int bb2 = rbase >> 11, ll = rbase & (SEQL - 1);
                s16x4 v4;
                v4[0] = (short)f2bf(acc[mi][ni][0] + bz);
                v4[1] = (short)f2bf(acc[mi][ni][1] + bz);
                v4[2] = (short)f2bf(acc[mi][ni][2] + bz);
                v4[3] = (short)f2bf(acc[mi][ni][3] + bz);
                *(s16x4*)(vtb + ((size_t)((bb2 * NH + h) * HD + d)) * SEQL + ll) = v4;
            }
        }
    }
}

// ---------------------------------------------------------------------------
// 128x128-tile NT GEMM -- out-proj only (grid 256 = 32mt x 8nt).
// R12 change: 2D XCD chunk (8mt x 4nt per XCD -> 2 MB A + 1 MB B, L2-fit).
// mt = (xcd&3)*8 + (i2&7), nt = (xcd>>2)*4 + (i2>>3). Rest unchanged.
// ---------------------------------------------------------------------------
__global__ __launch_bounds__(256) void gemm_tile(
    const unsigned short* __restrict__ A, int astride,
    const unsigned short* __restrict__ Wb,
    const float* __restrict__ bias,
    unsigned short* qk, unsigned short* vtb, float* outf, int mode)
{
    __shared__ __align__(16) unsigned short Asm[3][128 * 32];   // 3x8 KB
    __shared__ __align__(16) unsigned short Bsm[3][128 * 32];   // 3x8 KB

    const int t    = threadIdx.x;
    const int lane = t & 63;
    const int l15  = lane & 15;
    const int quad = lane >> 4;
    const int w    = t >> 6;
    const int mrow = (w & 1) * 64;
    const int ncol = (w >> 1) * 64;
    // 2D XCD-chunked bijective mapping for the 32x8 grid
    const int xcd = blockIdx.x & 7;
    const int i2  = blockIdx.x >> 3;             // 0..31
    const int mt  = (xcd & 3) * 8 + (i2 & 7);    // 0..31
    const int nt  = (xcd >> 2) * 4 + (i2 >> 3);  // 0..7
    const int row0 = mt * 128;

    const unsigned short* ga = A  + (size_t)(row0 + (t >> 2)) * astride + (t & 3) * 8;
    const unsigned short* gb = Wb + (size_t)(nt * 128 + (t >> 2)) * DIMC + (t & 3) * 8;
    const size_t gaStep = (size_t)64 * astride;
    const size_t gbStep = (size_t)64 * DIMC;

    f32x4 acc[4][4] = {};

    auto stage = [&](unsigned short* Ab, unsigned short* Bb, int k0) {
        gld_lds16(ga + k0,          Ab + t * 8);
        gld_lds16(ga + gaStep + k0, Ab + 2048 + t * 8);
        gld_lds16(gb + k0,          Bb + t * 8);
        gld_lds16(gb + gbStep + k0, Bb + 2048 + t * 8);
    };

    auto compute = [&](const unsigned short* Ac, const unsigned short* Bc) {
        s16x8 a[4], b[4];
#pragma unroll
        for (int mi = 0; mi < 4; ++mi)
            a[mi] = *(const s16x8*)(Ac + (mrow + mi * 16 + l15) * 32 + quad * 8);
#pragma unroll
        for (int ni = 0; ni < 4; ++ni)
            b[ni] = *(const s16x8*)(Bc + (ncol + ni * 16 + l15) * 32 + quad * 8);
        __builtin_amdgcn_s_setprio(1);
#pragma unroll
        for (int mi = 0; mi < 4; ++mi)
#pragma unroll
            for (int ni = 0; ni < 4; ++ni)
                acc[mi][ni] = __builtin_amdgcn_mfma_f32_16x16x32_bf16(
                    a[mi], b[ni], acc[mi][ni], 0, 0, 0);
        __builtin_amdgcn_s_setprio(0);
    };

    stage(Asm[0], Bsm[0], 0);
    stage(Asm[1], Bsm[1], 32);

#pragma unroll 1
    for (int k0 = 0; k0 < 960; k0 += 96) {
        stage(Asm[2], Bsm[2], k0 + 64);
        WAITVM8();
        BAR();
        compute(Asm[0], Bsm[0]);
        BAR();
        stage(Asm[0], Bsm[0], k0 + 96);
        WAITVM8();
        BAR();
        compute(Asm[1], Bsm[1]);
        BAR();
        stage(Asm[1], Bsm[1], k0 + 128);
        WAITVM8();
        BAR();
        compute(Asm[2], Bsm[2]);
        BAR();
    }
    WAITVM4();
    BAR();
    compute(Asm[0], Bsm[0]);
    BAR();
    WAITVM0();
    BAR();
    compute(Asm[1], Bsm[1]);

    const int proj = nt >> 3;                  // 0 for the out-proj call
#pragma unroll
    for (int ni = 0; ni < 4; ++ni) {
        const int cq = (nt & 7) * 128 + ncol + ni * 16 + l15;
        const float bz = bias[proj * 1024 + cq];
#pragma unroll
        for (int mi = 0; mi < 4; ++mi) {
            const int rbase = row0 + mrow + mi * 16 + quad * 4;
            if (mode == 0) {
                if (proj < 2) {
                    const float scale = (proj == 0) ? QSCALE : 1.0f;
#pragma unroll
                    for (int r = 0; r < 4; ++r)
                        qk[(size_t)(rbase + r) * XSTR + proj * DIMC + cq] =
                            f2bf((acc[mi][ni][r] + bz) * scale);
                } else {
                    const int h = cq >> 6, d = cq & 63;
                    const int bb = rbase >> 11, ll = rbase & (SEQL - 1);
                    s16x4 v4;
                    v4[0] = (short)f2bf(acc[mi][ni][0] + bz);
                    v4[1] = (short)f2bf(acc[mi][ni][1] + bz);
                    v4[2] = (short)f2bf(acc[mi][ni][2] + bz);
                    v4[3] = (short)f2bf(acc[mi][ni][3] + bz);
                    *(s16x4*)(vtb + ((size_t)((bb * NH + h) * HD + d)) * SEQL + ll) = v4;
                }
            } else {
#pragma unroll
                for (int r = 0; r < 4; ++r)
                    outf[(size_t)(rbase + r) * DIMC + cq] = acc[mi][ni][r] + bz;
            }
        }
    }
}

// ---------------------------------------------------------------------------
// Flash attention v11 (R9/R11 PASSED version, byte-identical). UNCHANGED.
// ---------------------------------------------------------------------------
__global__ __launch_bounds__(256) void attn_fused(
    unsigned short* xqk,
    const unsigned short* __restrict__ vt)
{
    __shared__ __align__(16) unsigned short Ksm[2][2][64 * 64];   // 32 KB
    __shared__ __align__(16) unsigned short Vsm[2][2][64 * 64];   // 32 KB

    const int t    = threadIdx.x;
    const int lane = t & 63;
    const int l15  = lane & 15;
    const int quad = lane >> 4;
    const int w    = t >> 6;                 // wave 0..3

    // XCD-pinned mapping (bijective: bid = ii*8 + xcd), 512 blocks
    const int xcd = blockIdx.x & 7;
    const int ii  = blockIdx.x >> 3;         // 0..63
    const int bh  = (xcd << 2) | (ii >> 4);  // all 16 q-blocks of a bh on one XCD
    const int qb  = ii & 15;                 // 128-row q-block
    const int h  = bh & (NH - 1);
    const int bb = bh >> 4;
    const int q0A = qb * 128 + w * 16;       // wave's two q-tiles
    const int q0B = q0A + 64;

    // Q B-frags (lane&15 = q row), loaded before any O store (in-place safe)
    unsigned short* qbase = xqk + (size_t)(bb * SEQL) * XSTR + h * HD + quad * 8;
    unsigned short* qrA = qbase + (size_t)(q0A + l15) * XSTR;
    unsigned short* qrB = qbase + (size_t)(q0B + l15) * XSTR;
    const s16x8 bqA0 = ld8(qrA), bqA1 = ld8(qrA + 32);
    const s16x8 bqB0 = ld8(qrB), bqB1 = ld8(qrB + 32);

    // all-ones bf16 B-frag for the l-accumulation MFMA
    s16x8 bones;
#pragma unroll
    for (int e = 0; e < 8; ++e) bones[e] = (short)0x3F80;

    // staging: 256 threads cover a 64x64 tile in 2 row-groups of 32.
    const int tr = t >> 3, tp = t & 7;
    const int swz = (tp ^ (tr & 7)) * 8;
    const unsigned short* kg = xqk + (size_t)bb * SEQL * XSTR + DIMC + h * HD
                               + (size_t)tr * XSTR + swz;
    const unsigned short* vg = vt + (size_t)(bh * HD + tr) * SEQL + swz;

    f32x4 oA[4] = {}, oB[4] = {};
    f32x4 laccA = {}, laccB = {};            // row-sums of P (denominators)
    const int xk = l15 & 7;

    // stage one 64-key tile (K + V); 4 loads per thread
    auto stage = [&](unsigned short* Kb, unsigned short* Vb, int j) {
#pragma unroll
        for (int g = 0; g < 2; ++g) {
            gld_lds16(kg + (size_t)(j + g * 32) * XSTR, Kb + g * 2048 + t * 8);
            gld_lds16(vg + (size_t)(g * 32) * SEQL + j,  Vb + g * 2048 + t * 8);
        }
    };

    // compute one 64-key tile from buffers
    auto compute = [&](const unsigned short* Kc, const unsigned short* Vc) {
#pragma unroll
        for (int hf = 0; hf < 2; ++hf) {
            const int k0 = (hf * 32 + l15) * 64;
            const int k1 = (hf * 32 + 16 + l15) * 64;
            s16x8 a00 = *(const s16x8*)(Kc + k0 + ((quad       ^ xk) * 8));
            s16x8 a01 = *(const s16x8*)(Kc + k0 + (((quad + 4) ^ xk) * 8));
            s16x8 a10 = *(const s16x8*)(Kc + k1 + ((quad       ^ xk) * 8));
            s16x8 a11 = *(const s16x8*)(Kc + k1 + (((quad + 4) ^ xk) * 8));

            s16x8 bv[4];
#pragma unroll
            for (int c = 0; c < 4; ++c) {
                const unsigned short* va = Vc + (c * 16 + l15) * 64 + (quad & 1) * 4;
                const int kc0 = hf * 4 + (quad >> 1);
                s16x4 v0 = *(const s16x4*)(va + ((kc0       ^ xk) * 8));
                s16x4 v1 = *(const s16x4*)(va + (((kc0 + 2) ^ xk) * 8));
                bv[c] = __builtin_shufflevector(v0, v1, 0, 1, 2, 3, 4, 5, 6, 7);
            }

            __builtin_amdgcn_s_setprio(1);
            // q-tile A
            {
                f32x4 st0 = {}, st1 = {};
                st0 = __builtin_amdgcn_mfma_f32_16x16x32_bf16(a00, bqA0, st0, 0, 0, 0);
                st0 = __builtin_amdgcn_mfma_f32_16x16x32_bf16(a01, bqA1, st0, 0, 0, 0);
                st1 = __builtin_amdgcn_mfma_f32_16x16x32_bf16(a10, bqA0, st1, 0, 0, 0);
                st1 = __builtin_amdgcn_mfma_f32_16x16x32_bf16(a11, bqA1, st1, 0, 0, 0);
                i32x4 api;
                api[0] = (int)cvtpk(__builtin_amdgcn_exp2f(st0[0]),
                                    __builtin_amdgcn_exp2f(st0[1]));
                api[1] = (int)cvtpk(__builtin_amdgcn_exp2f(st0[2]),
                                    __builtin_amdgcn_exp2f(st0[3]));
                api[2] = (int)cvtpk(__builtin_amdgcn_exp2f(st1[0]),
                                    __builtin_amdgcn_exp2f(st1[1]));
                api[3] = (int)cvtpk(__builtin_amdgcn_exp2f(st1[2]),
                                    __builtin_amdgcn_exp2f(st1[3]));
                s16x8 ap = __builtin_bit_cast(s16x8, api);
                laccA = __builtin_amdgcn_mfma_f32_16x16x32_bf16(ap, bones, laccA, 0, 0, 0);
#pragma unroll
                for (int c = 0; c < 4; ++c)
                    oA[c] = __builtin_amdgcn_mfma_f32_16x16x32_bf16(ap, bv[c], oA[c], 0, 0, 0);
            }
            // q-tile B
            {
                f32x4 st0 = {}, st1 = {};
                st0 = __builtin_amdgcn_mfma_f32_16x16x32_bf16(a00, bqB0, st0, 0, 0, 0);
                st0 = __builtin_amdgcn_mfma_f32_16x16x32_bf16(a01, bqB1, st0, 0, 0, 0);
                st1 = __builtin_amdgcn_mfma_f32_16x16x32_bf16(a10, bqB0, st1, 0, 0, 0);
                st1 = __builtin_amdgcn_mfma_f32_16x16x32_bf16(a11, bqB1, st1, 0, 0, 0);
                i32x4 api;
                api[0] = (int)cvtpk(__builtin_amdgcn_exp2f(st0[0]),
                                    __builtin_amdgcn_exp2f(st0[1]));
                api[1] = (int)cvtpk(__builtin_amdgcn_exp2f(st0[2]),
                                    __builtin_amdgcn_exp2f(st0[3]));
                api[2] = (int)cvtpk(__builtin_amdgcn_exp2f(st1[0]),
                                    __builtin_amdgcn_exp2f(st1[1]));
                api[3] = (int)cvtpk(__builtin_amdgcn_exp2f(st1[2]),
                                    __builtin_amdgcn_exp2f(st1[3]));
                s16x8 ap = __builtin_bit_cast(s16x8, api);
                laccB = __builtin_amdgcn_mfma_f32_16x16x32_bf16(ap, bones, laccB, 0, 0, 0);
#pragma unroll
                for (int c = 0; c < 4; ++c)
                    oB[c] = __builtin_amdgcn_mfma_f32_16x16x32_bf16(ap, bv[c], oB[c], 0, 0, 0);
            }
            __builtin_amdgcn_s_setprio(0);
        }
    };

    // prologue: stage both halves of window 0 into buffer 0 (8 loads)
    stage(Ksm[0][0], Vsm[0][0], 0);
    stage(Ksm[0][1], Vsm[0][1], 64);

    // main loop over 16 x 128-key windows, unroll-2 (compile-time buffers).
#pragma unroll 1
    for (int jt = 0; jt < SEQL / 128; jt += 2) {
        const int j0 = jt * 128;
        // body A: prefetch window jt+1 -> buf1, compute buf0 (window jt)
        stage(Ksm[1][0], Vsm[1][0], j0 + 128);
        stage(Ksm[1][1], Vsm[1][1], j0 + 192);
        WAITVM8();
        BAR();
        compute(Ksm[0][0], Vsm[0][0]);
        compute(Ksm[0][1], Vsm[0][1]);
        BAR();
        // body B: prefetch window jt+2 -> buf0, compute buf1 (window jt+1)
        if (jt + 2 < SEQL / 128) {
            stage(Ksm[0][0], Vsm[0][0], j0 + 256);
            stage(Ksm[0][1], Vsm[0][1], j0 + 320);
            WAITVM8();
        } else {
            WAITVM0();
        }
        BAR();
        compute(Ksm[1][0], Vsm[1][0]);
        compute(Ksm[1][1], Vsm[1][1]);
        BAR();
    }

    // laccX[r] = l for q-row quad*4+r (replicated across l15) -> no shuffles
    float liA[4], liB[4];
#pragma unroll
    for (int r = 0; r < 4; ++r) {
        liA[r] = 1.0f / laccA[r];
        liB[r] = 1.0f / laccB[r];
    }

#pragma unroll
    for (int c = 0; c < 4; ++c) {
        const int d = c * 16 + l15;
#pragma unroll
        for (int r = 0; r < 4; ++r) {
            const int qr = quad * 4 + r;
            xqk[(size_t)(bb * SEQL + q0A + qr) * XSTR + h * HD + d] = f2bf(oA[c][r] * liA[r]);
            xqk[(size_t)(bb * SEQL + q0B + qr) * XSTR + h * HD + d] = f2bf(oB[c][r] * liB[r]);
        }
    }
}

// ---------------------------------------------------------------------------
// Launcher: exact R9 (xqk = d_in[0]; ws-xqk was perf-null in R11 and distorts
// profiling). ws layout (u16): xb [0,4M) | Wq..Wp [4M,8M) | bias fp32 @ 8M.
// ---------------------------------------------------------------------------
extern "C" void kernel_launch(void* const* d_in, const int* in_sizes, int n_in,
                              void* d_out, int out_size, void* d_ws, size_t ws_size,
                              hipStream_t stream) {
    const float* x  = (const float*)d_in[0];
    const float* Wq = (const float*)d_in[1];
    const float* bq = (const float*)d_in[2];
    const float* Wk = (const float*)d_in[3];
    const float* bk = (const float*)d_in[4];
    const float* Wv = (const float*)d_in[5];
    const float* bv = (const float*)d_in[6];
    const float* Wp = (const float*)d_in[7];
    const float* bp = (const float*)d_in[8];
    float* out = (float*)d_out;
    unsigned short* vtb = (unsigned short*)d_out;
    unsigned short* xqk = (unsigned short*)d_in[0];

    unsigned short* ws   = (unsigned short*)d_ws;
    const size_t XELT = (size_t)MTOT * DIMC;     // 4M u16
    const size_t WELT = (size_t)DIMC * DIMC;     // 1M u16
    unsigned short* xb   = ws;
    unsigned short* wall = ws + XELT;
    float*          ball = (float*)(ws + 2 * XELT);

    // allow 128 KB dynamic LDS for qkv8 (one-time)
    static bool ldsInit = false;
    if (!ldsInit) {
        (void)hipFuncSetAttribute((const void*)qkv8,
                                  hipFuncAttributeMaxDynamicSharedMemorySize,
                                  131072);
        ldsInit = true;
    }

    cast_all<<<8204, 256, 0, stream>>>(x, Wq, Wk, Wv, Wp, bq, bk, bv, xb, wall, ball);

    // fused QKV GEMM: M=4096, N=3072 -> 16 x 12 tiles of 256^2 = 192 blocks
    qkv8<<<192, 512, 131072, stream>>>(xb, wall, ball, xqk, vtb);

    // attention: 512 blocks (32 bh x 16 q-blocks of 128 rows), 4 waves each
    attn_fused<<<NB * NH * (SEQL / 128), 256, 0, stream>>>(xqk, vtb);

    // out-proj: M=4096, N=1024 -> 256 blocks, fp32 out
    gemm_tile<<<256, 256, 0, stream>>>(xqk, XSTR, wall + 3 * WELT, bp,
                                       nullptr, nullptr, out, 1);
}